// Round 7
// baseline (58.710 us; speedup 1.0000x reference)
//
#include <hip/hip_runtime.h>

// SphericalEmbedding round 7: R6 + XCD-bijective block swizzle (T1) so each
// XCD owns a contiguous output row-band (its L2 assembles full 8KB rows ->
// full-row HBM bursts instead of 512B fragments from 8 XCDs), + chunked
// C-staging reusing the H LDS region (26.6KB, occupancy up), + constant-
// reciprocal Legendre (no v_div chains).

typedef __attribute__((ext_vector_type(8))) short bf16x8;
typedef __attribute__((ext_vector_type(4))) float f32x4;

#define BM 128           // points per block
#define BN 128           // channels per block
#define LDA 104          // H row stride (bf16): 208 B -> 2-way aliasing (free)
#define KPAD 96
#define LDCC 132         // C chunk row stride (dwords)

// ---- compile-time normalization table ----------------------------------
constexpr double PI_D = 3.14159265358979323846;
constexpr double csqrt_c(double v) {
  if (v <= 0.0) return 0.0;
  double g = v < 1.0 ? 1.0 : v;
  for (int i = 0; i < 100; ++i) g = 0.5 * (g + v / g);
  return g;
}
struct Norms { float c[81]; };
constexpr Norms make_norms() {
  Norms n{};
  for (int l = 0; l <= 8; ++l)
    for (int m = -l; m <= l; ++m) {
      int am = m < 0 ? -m : m;
      double fr = 1.0;
      for (int i = l - am + 1; i <= l + am; ++i) fr *= (double)i;
      double v = csqrt_c((2.0 * l + 1.0) / (4.0 * PI_D) / fr);
      if (m < 0 && (am & 1)) v = -v;
      n.c[l * l + l + m] = (float)v;
    }
  return n;
}
constexpr Norms NORMS = make_norms();

__device__ __forceinline__ unsigned f2bf(float f) {   // RTN-even f32 -> bf16 bits
  unsigned u = __float_as_uint(f);
  return (u + 0x7fffu + ((u >> 16) & 1u)) >> 16;
}

// ---- pre-kernel: W f32 [81][nch] -> WT bf16 [nch][96] (padded) ---------
__global__ __launch_bounds__(256)
void wt_convert_kernel(const float* __restrict__ W, unsigned short* __restrict__ WT, int nch) {
  const int t = blockIdx.x * 256 + threadIdx.x;    // t in [0, nch*12)
  if (t >= nch * 12) return;
  const int kg = t / nch;                          // k-group of 8 (0..11)
  const int c  = t - kg * nch;                     // lanes -> consecutive c (coalesced)
  unsigned short v[8];
#pragma unroll
  for (int j = 0; j < 8; ++j) {
    const int k = kg * 8 + j;
    v[j] = (k < 81) ? (unsigned short)f2bf(W[(size_t)k * nch + c]) : (unsigned short)0;
  }
  unsigned* dst = reinterpret_cast<unsigned*>(WT + (size_t)c * KPAD + kg * 8);
#pragma unroll
  for (int j = 0; j < 4; ++j)
    dst[j] = (unsigned)v[2 * j] | ((unsigned)v[2 * j + 1] << 16);
}

// ---- main MFMA kernel ---------------------------------------------------
__global__ __launch_bounds__(256)
void sph_mfma_kernel(const float* __restrict__ pos,
                     const unsigned short* __restrict__ WT,
                     float* __restrict__ out, int nch, int nbx)
{
  // H (bf16, 26.6 KB) and per-pn C chunk (32x132 f32 = 16.9 KB) time-share.
  __shared__ __align__(16) char smem[BM * LDA * 2];        // 26624 B
  unsigned short* H = reinterpret_cast<unsigned short*>(smem);
  float*          C = reinterpret_cast<float*>(smem);

  // XCD-bijective swizzle: each XCD gets a contiguous wgid chunk; decompose
  // nblk-fastest so one XCD owns a contiguous output row-band.
  const int nwg  = gridDim.x;
  const int orig = blockIdx.x;
  const int wgid = ((nwg & 7) == 0) ? (orig & 7) * (nwg >> 3) + (orig >> 3) : orig;
  const int mblk = wgid / nbx;
  const int nblk = wgid - mblk * nbx;

  const int tid  = threadIdx.x;
  const int lane = tid & 63;
  const int wid  = tid >> 6;                       // 4 waves: 2(ch) x 2(pt)
  const int wc   = wid >> 1, wp = wid & 1;
  const int l15  = lane & 15, l4 = lane >> 4;

  // ---- phase 1: harmonics for 128 points -> bf16 rows in LDS -----------
  if (tid < BM) {
    const int gp = mblk * BM + tid;
    const float px = pos[gp * 3 + 0];
    const float py = pos[gp * 3 + 1];
    const float pz = pos[gp * 3 + 2];
    const float r   = sqrtf(px * px + py * py + pz * pz);
    const float inv = 1.0f / (r + 1e-8f);
    const float xn = px * inv, yn = py * inv, zn = pz * inv;
    const float x = fminf(1.0f, fmaxf(-1.0f, zn));     // cos(theta)
    const float s = sqrtf(fmaxf(0.0f, 1.0f - x * x));  // sin(theta)
    const float rho2 = xn * xn + yn * yn;
    const float c1   = rho2 > 0.0f ? xn * rsqrtf(rho2) : 1.0f;   // cos(phi)

    float cm[9];
    cm[0] = 1.0f; cm[1] = c1;
#pragma unroll
    for (int m = 2; m <= 8; ++m) cm[m] = 2.0f * c1 * cm[m - 1] - cm[m - 2];

    float P[9][9];
#pragma unroll
    for (int m = 0; m <= 8; ++m) {
      if (m == 0) P[0][0] = 1.0f;
      else        P[m][m] = -(float)(2 * m - 1) * s * P[m - 1][m - 1];
      if (m + 1 <= 8) P[m + 1][m] = (float)(2 * m + 1) * x * P[m][m];
#pragma unroll
      for (int l = m + 2; l <= 8; ++l)
        P[l][m] = ((float)(2 * l - 1) * x * P[l - 1][m]
                   - (float)(l + m - 1) * P[l - 2][m]) * (1.0f / (float)(l - m));
    }

    float y[KPAD];
#pragma unroll
    for (int l = 0; l <= 8; ++l)
#pragma unroll
      for (int m = -l; m <= l; ++m) {
        const int am  = m < 0 ? -m : m;
        const int idx = l * l + l + m;
        y[idx] = NORMS.c[idx] * P[l][am] * cm[am];
      }
#pragma unroll
    for (int i = 81; i < KPAD; ++i) y[i] = 0.0f;

    unsigned* hrow = reinterpret_cast<unsigned*>(&H[tid * LDA]);
#pragma unroll
    for (int i = 0; i < KPAD / 2; ++i)
      hrow[i] = f2bf(y[2 * i]) | (f2bf(y[2 * i + 1]) << 16);
  }

  // ---- A fragments: W channels, direct 16B global loads (L2-resident) --
  bf16x8 wfrag[3][4];
  const unsigned short* wt_base =
      WT + (size_t)(nblk * BN + wc * 64 + l15) * KPAD + l4 * 8;
#pragma unroll
  for (int kk = 0; kk < 3; ++kk)
#pragma unroll
    for (int cmr = 0; cmr < 4; ++cmr)
      wfrag[kk][cmr] = *reinterpret_cast<const bf16x8*>(
          wt_base + (size_t)cmr * 16 * KPAD + kk * 32);

  __syncthreads();

  // ---- MFMA: D[ch, pt], 3 k-steps, 4x4 16x16 tiles per wave -------------
  f32x4 acc[4][4] = {};
#pragma unroll
  for (int kk = 0; kk < 3; ++kk) {
    bf16x8 hfrag[4];
#pragma unroll
    for (int pn = 0; pn < 4; ++pn)
      hfrag[pn] = *reinterpret_cast<const bf16x8*>(
          &H[(wp * 64 + pn * 16 + l15) * LDA + kk * 32 + l4 * 8]);
#pragma unroll
    for (int cmr = 0; cmr < 4; ++cmr)
#pragma unroll
      for (int pn = 0; pn < 4; ++pn)
        acc[cmr][pn] = __builtin_amdgcn_mfma_f32_16x16x32_bf16(
            wfrag[kk][cmr], hfrag[pn], acc[cmr][pn], 0, 0, 0);
  }

  __syncthreads();   // H is dead; smem becomes per-pn C chunks

  // ---- epilogue: per pn chunk (32 rows x 128 ch), stage -> linear drain --
  const size_t obase = (size_t)(mblk * BM) * nch + (size_t)nblk * BN;
#pragma unroll
  for (int pn = 0; pn < 4; ++pn) {
    // stage: D row(ch) = l4*4+reg (+16*cmr), D col(pt) = l15 (+16*pn)
    // chunk row index = wp*16 + l15 (0..31)
#pragma unroll
    for (int cmr = 0; cmr < 4; ++cmr)
      *reinterpret_cast<f32x4*>(
          &C[(wp * 16 + l15) * LDCC + wc * 64 + cmr * 16 + l4 * 4]) = acc[cmr][pn];
    __syncthreads();

    // drain: 4096 floats, 4 iters x (256 threads x f32x4)
#pragma unroll
    for (int i = 0; i < 4; ++i) {
      const int idx = (i * 256 + tid) * 4;           // flat float idx in chunk
      const int cr  = idx >> 7;                      // chunk row 0..31
      const int cc  = idx & 127;                     // channel col
      const int wpg = cr >> 4;                       // which wp half
      const int lrow = wpg * 64 + pn * 16 + (cr & 15);
      const f32x4 v = *reinterpret_cast<const f32x4*>(&C[cr * LDCC + cc]);
      *reinterpret_cast<f32x4*>(out + obase + (size_t)lrow * nch + cc) = v;
    }
    if (pn < 3) __syncthreads();
  }
}

extern "C" void kernel_launch(void* const* d_in, const int* in_sizes, int n_in,
                              void* d_out, int out_size, void* d_ws, size_t ws_size,
                              hipStream_t stream) {
  const float* pos = (const float*)d_in[0];   // [npts, 3]
  const float* W   = (const float*)d_in[1];   // [81, nch]
  float*       out = (float*)d_out;           // [npts, nch]
  const int npts = in_sizes[0] / 3;           // 32768
  const int nch  = in_sizes[1] / 81;          // 2048

  unsigned short* WT = (unsigned short*)d_ws;  // 384 KB
  const int cvt_threads = nch * 12;
  wt_convert_kernel<<<(cvt_threads + 255) / 256, 256, 0, stream>>>(W, WT, nch);

  const int nbx = nch / BN;                    // 16
  const int nwg = nbx * (npts / BM);           // 4096
  sph_mfma_kernel<<<nwg, 256, 0, stream>>>(pos, WT, out, nch, nbx);
}